// Round 8
// baseline (111.266 us; speedup 1.0000x reference)
//
#include <hip/hip_runtime.h>
#include <hip/hip_fp16.h>
#include <stdint.h>

#define NN 8192          // nodes
#define HID 256          // hidden
#define NH 4             // heads
#define HD 64            // head dim
#define NE 262144        // edges
#define WPR (NN / 32)    // bitmap words per row = 256
#define CAP 128          // max neighbors per row (Binomial(262k,1/8192): max ~57)
#define K2 768           // split-K' = 3*256
#define NQKV 768         // fused QKV output width
#define SPAD 160         // padded list length (batch-8 overrun: j <= 126+28 < 160)

typedef __attribute__((ext_vector_type(8))) short s16x8;      // 8 bf16 (4 VGPRs)
typedef __attribute__((ext_vector_type(4))) float f32x4;      // MFMA C/D frag
typedef _Float16 f16x2 __attribute__((ext_vector_type(2)));   // v_dot2 operand

__device__ __forceinline__ float fdot2(f16x2 a, f16x2 b, float c) {
#if __has_builtin(__builtin_amdgcn_fdot2)
    return __builtin_amdgcn_fdot2(a, b, c, false);
#else
    return c + (float)a.x * (float)b.x + (float)a.y * (float)b.y;
#endif
}

__device__ __forceinline__ unsigned short f2bf(float x) {  // RNE fp32->bf16
    unsigned u = __float_as_uint(x);
    u += 0x7FFFu + ((u >> 16) & 1u);
    return (unsigned short)(u >> 16);
}
__device__ __forceinline__ float bf2f(unsigned short b) {
    return __uint_as_float(((unsigned)b) << 16);
}

__device__ __forceinline__ void gload_lds16(const unsigned short* g, unsigned short* l) {
    __builtin_amdgcn_global_load_lds(
        (const __attribute__((address_space(1))) unsigned int*)g,
        (__attribute__((address_space(3))) unsigned int*)l, 16, 0, 0);
}

// ---------------------------------------------------------------------------
// Zero the bitmap (replaces hipMemsetAsync; guaranteed BW-bound dispatch)
// 2048 blocks x 256 thr x 16B = 8 MB
// ---------------------------------------------------------------------------
__global__ __launch_bounds__(256) void zero_kernel(uint4* __restrict__ p)
{
    p[blockIdx.x * 256 + threadIdx.x] = make_uint4(0, 0, 0, 0);
}

// ---------------------------------------------------------------------------
// Fused prep: [0,1024) edge scatter | [1024,9216) X split | [9216,12288) W split
// ---------------------------------------------------------------------------
__global__ __launch_bounds__(256) void prep_kernel(
    const float* __restrict__ X,
    const float* __restrict__ Wq, const float* __restrict__ Wk,
    const float* __restrict__ Wv, const float* __restrict__ Wo,
    const float* __restrict__ bq, const float* __restrict__ bk,
    const float* __restrict__ bv, const int* __restrict__ ei,
    uint32_t* __restrict__ bitmap, unsigned short* __restrict__ A2,
    unsigned short* __restrict__ W2Tq, unsigned short* __restrict__ W2To,
    float* __restrict__ biasq)
{
    const int b = blockIdx.x, tid = threadIdx.x;
    if (b < 1024) {                                   // ---- edge scatter ----
        int e = b * 256 + tid;
        int r = ei[e];
        int c = ei[NE + e];
        atomicOr(&bitmap[(size_t)r * WPR + (c >> 5)], 1u << (c & 31));
    } else if (b < 1024 + 8192) {                     // ---- X -> [X_hi|X_lo] ----
        int idx = (b - 1024) * 256 + tid;
        int r = idx >> 8, c = idx & 255;
        float x = X[idx];
        unsigned short hi = f2bf(x);
        A2[(size_t)r * 512 + c]       = hi;
        A2[(size_t)r * 512 + 256 + c] = f2bf(x - bf2f(hi));
    } else {                                          // ---- W^T split ----
        int bb = b - 9216;                            // [0, 3072)
        int n  = bb & 1023;
        int kp = (bb >> 10) * 256 + tid;              // 0..767
        const float* W; int ns; unsigned short* dst;
        if (n < NQKV) {
            W  = (n < 256) ? Wq : (n < 512) ? Wk : Wv;
            ns = n & 255;
            dst = W2Tq + (size_t)n * K2;
            if ((bb >> 10) == 0 && tid == 0) {
                const float* bsrc = (n < 256) ? bq : (n < 512) ? bk : bv;
                biasq[n] = bsrc[ns];
            }
        } else {
            W = Wo; ns = n - NQKV;
            dst = W2To + (size_t)ns * K2;
        }
        float w = W[(size_t)(kp & 255) * HID + ns];
        unsigned short hi = f2bf(w);
        dst[kp] = (kp < 512) ? hi : f2bf(w - bf2f(hi));
    }
}

// ---------------------------------------------------------------------------
// Split-bf16 MFMA GEMM: C[8192][N] = A''[8192][768] * B''[768][N] + bias
// BM=128 fixed; BN template (128 QKV / 64 out-proj). 4 waves 2x2; 16x16x32.
// 1D grid + bijective XCD swizzle (nwg % 8 == 0).
// ---------------------------------------------------------------------------
template<int BN, bool HALF_OUT>
__global__ __launch_bounds__(256) void mfma_gemm_kernel(
    const unsigned short* __restrict__ A2, const unsigned short* __restrict__ BT,
    const float* __restrict__ bias, void* __restrict__ Cv, int N)
{
    constexpr int NFR = BN / 32;                    // N-frags per wave
    __shared__ __align__(16) unsigned short Alds[128 * 32];
    __shared__ __align__(16) unsigned short Blds[BN * 32];

    const int tid  = threadIdx.x;
    const int lane = tid & 63, wave = tid >> 6;
    const int wm = wave >> 1, wn = wave & 1;

    const int nwg = gridDim.x;
    const int orig = blockIdx.x;
    const int q8 = nwg >> 3;
    const int id = (orig & 7) * q8 + (orig >> 3);   // XCD-contiguous chunks
    const int m0 = (id & 63) * 128;                 // 64 M-tiles (8192/128)
    const int n0 = (id >> 6) * BN;

    const int r0 = tid >> 2, cc0 = tid & 3;
    const int r1 = (tid + 256) >> 2, cc1 = (tid + 256) & 3;

    f32x4 acc[4][NFR];
    #pragma unroll
    for (int i = 0; i < 4; ++i)
        #pragma unroll
        for (int j = 0; j < NFR; ++j)
            acc[i][j] = (f32x4){0.f, 0.f, 0.f, 0.f};

    for (int step = 0; step < 24; ++step) {
        const int kk = step * 32;
        const int ka = kk & 511;                    // A'' column base ([Ahi|Alo|Ahi])
        __syncthreads();
        gload_lds16(A2 + (size_t)(m0 + r0) * 512 + ka + cc0 * 8, &Alds[tid * 8]);
        gload_lds16(A2 + (size_t)(m0 + r1) * 512 + ka + cc1 * 8, &Alds[(tid + 256) * 8]);
        gload_lds16(BT + (size_t)(n0 + r0) * K2 + kk + cc0 * 8, &Blds[tid * 8]);
        if constexpr (BN == 128)
            gload_lds16(BT + (size_t)(n0 + r1) * K2 + kk + cc1 * 8, &Blds[(tid + 256) * 8]);
        __syncthreads();

        s16x8 af[4], bfr[NFR];
        #pragma unroll
        for (int i = 0; i < 4; ++i)
            af[i] = *(const s16x8*)&Alds[(wm * 64 + i * 16 + (lane & 15)) * 32 + (lane >> 4) * 8];
        #pragma unroll
        for (int j = 0; j < NFR; ++j)
            bfr[j] = *(const s16x8*)&Blds[(wn * (BN / 2) + j * 16 + (lane & 15)) * 32 + (lane >> 4) * 8];
        #pragma unroll
        for (int i = 0; i < 4; ++i)
            #pragma unroll
            for (int j = 0; j < NFR; ++j)
                acc[i][j] = __builtin_amdgcn_mfma_f32_16x16x32_bf16(af[i], bfr[j], acc[i][j], 0, 0, 0);
    }

    // epilogue: C/D layout col=lane&15, row=(lane>>4)*4+reg
    #pragma unroll
    for (int i = 0; i < 4; ++i) {
        #pragma unroll
        for (int j = 0; j < NFR; ++j) {
            int gcol = n0 + wn * (BN / 2) + j * 16 + (lane & 15);
            float bb = bias[gcol];
            #pragma unroll
            for (int r = 0; r < 4; ++r) {
                int grow = m0 + wm * 64 + i * 16 + (lane >> 4) * 4 + r;
                float v = acc[i][j][r] + bb;
                if constexpr (HALF_OUT)
                    ((__half*)Cv)[(size_t)grow * N + gcol] = __float2half(v);
                else
                    ((float*)Cv)[(size_t)grow * N + gcol] = v;
            }
        }
    }
}

// ---------------------------------------------------------------------------
// Compact bitmap rows into capped neighbor lists. One wave per row.
// ---------------------------------------------------------------------------
__global__ __launch_bounds__(256) void build_csr_kernel(
    const uint32_t* __restrict__ bitmap, int* __restrict__ nbr, int* __restrict__ cnt)
{
    const int row = blockIdx.x * 4 + (threadIdx.x >> 6);
    const int lane = threadIdx.x & 63;
    const uint32_t* rp = bitmap + (size_t)row * WPR + lane * 4;
    uint32_t w0 = rp[0], w1 = rp[1], w2 = rp[2], w3 = rp[3];
    int pc = __popc(w0) + __popc(w1) + __popc(w2) + __popc(w3);
    int scan = pc;
    #pragma unroll
    for (int off = 1; off < 64; off <<= 1) {
        int t = __shfl_up(scan, off);
        if (lane >= off) scan += t;
    }
    int idx = scan - pc;
    int* dst = nbr + (size_t)row * CAP;
    const int base = lane * 128;
    uint32_t ws4[4] = {w0, w1, w2, w3};
    #pragma unroll
    for (int i = 0; i < 4; ++i) {
        uint32_t w = ws4[i];
        int cb = base + i * 32;
        while (w) {
            int b = __ffs(w) - 1;
            if (idx < CAP) dst[idx] = cb + b;
            ++idx;
            w &= w - 1;
        }
    }
    if (lane == 63) cnt[row] = min(scan, CAP);
}

// ---------------------------------------------------------------------------
// Sparse attention, wave-per-neighbor coalesced gathers, batch-8 MLP.
// Fast path (cnt <= 64): K AND V batches loaded upfront; V kept in registers;
// post-softmax PV is pure register math (single gather round).
// Slow path (cnt > 64, ~never for this seed): re-gather V after softmax.
// Softmax weights stored pre-normalized (1/l folded in).
// ---------------------------------------------------------------------------
__global__ __launch_bounds__(256) void attn_kernel(
    const __half* __restrict__ QKV, const int* __restrict__ nbr,
    const int* __restrict__ cntg, unsigned short* __restrict__ Cm2)
{
    const int row  = blockIdx.x;
    const int tid  = threadIdx.x;
    const int lane = tid & 63;
    const int wv   = tid >> 6;
    const int g    = lane >> 4;        // head this lane's slice belongs to
    const int sub  = lane & 15;

    __shared__ __align__(16) unsigned short qs[HID];   // fp16 Q row (pre-scaled)
    __shared__ int   nbrs[SPAD];
    __shared__ float smat[NH][SPAD];                   // scores
    __shared__ float wls[NH][SPAD];                    // normalized weights
    __shared__ __align__(16) float ctxp[NH][HID];      // per-wave partial ctx

    {   // Q row, pre-scaled by 1/sqrt(64)=0.125 (power of 2: exact in fp16)
        __half qh = QKV[(size_t)row * NQKV + tid];
        qs[tid] = __half_as_ushort(__hmul(qh, __float2half(0.125f)));
    }
    const int cnt = cntg[row];
    if (tid < SPAD) nbrs[tid] = (tid < cnt) ? nbr[(size_t)row * CAP + tid] : 0;
    __syncthreads();

    if (cnt == 0) {
        Cm2[(size_t)row * 512 + tid] = 0;
        Cm2[(size_t)row * 512 + 256 + tid] = 0;
        return;
    }

    // per-lane Q slice: halves [4*lane, 4*lane+4) as 2x f16x2
    const f16x2* qs2 = (const f16x2*)qs;
    const f16x2 q2a = qs2[2 * lane], q2b = qs2[2 * lane + 1];

    float a0 = 0.f, a1 = 0.f, a2 = 0.f, a3 = 0.f;

    if (cnt <= 64) {
        // ======== FAST PATH: one gather round, V cached in registers ========
        const bool two = cnt > 32;
        uint2 kv0[8], vv0[8], kv1[8], vv1[8];
        #pragma unroll
        for (int u = 0; u < 8; ++u) {               // batch 0: 16 loads in flight
            const __half* base = QKV + (size_t)nbrs[wv + u * 4] * NQKV;
            kv0[u] = ((const uint2*)(base + 256))[lane];
            vv0[u] = ((const uint2*)(base + 512))[lane];
        }
        if (two) {
            #pragma unroll
            for (int u = 0; u < 8; ++u) {           // batch 1: +16 loads
                const __half* base = QKV + (size_t)nbrs[wv + 32 + u * 4] * NQKV;
                kv1[u] = ((const uint2*)(base + 256))[lane];
                vv1[u] = ((const uint2*)(base + 512))[lane];
            }
        }
        #pragma unroll
        for (int u = 0; u < 8; ++u) {
            union { uint2 u2; f16x2 h[2]; } uk; uk.u2 = kv0[u];
            float p = fdot2(q2a, uk.h[0], 0.f);
            p = fdot2(q2b, uk.h[1], p);
            #pragma unroll
            for (int off = 1; off < 16; off <<= 1) p += __shfl_xor(p, off);
            if (sub == 0) smat[g][wv + u * 4] = p;
        }
        if (two) {
            #pragma unroll
            for (int u = 0; u < 8; ++u) {
                union { uint2 u2; f16x2 h[2]; } uk; uk.u2 = kv1[u];
                float p = fdot2(q2a, uk.h[0], 0.f);
                p = fdot2(q2b, uk.h[1], p);
                #pragma unroll
                for (int off = 1; off < 16; off <<= 1) p += __shfl_xor(p, off);
                if (sub == 0) smat[g][wv + 32 + u * 4] = p;
            }
        }
        __syncthreads();

        {   // softmax per head (wave = head), normalized weights
            const int h = wv;
            float s0 = (lane < cnt)      ? smat[h][lane]      : -INFINITY;
            float s1 = (64 + lane < cnt) ? smat[h][64 + lane] : -INFINITY;
            float m = fmaxf(s0, s1);
            #pragma unroll
            for (int off = 32; off >= 1; off >>= 1) m = fmaxf(m, __shfl_xor(m, off));
            float e0 = expf(s0 - m);
            float e1 = expf(s1 - m);
            float l = e0 + e1;
            #pragma unroll
            for (int off = 32; off >= 1; off >>= 1) l += __shfl_xor(l, off);
            float rl = __frcp_rn(l);
            wls[h][lane]      = e0 * rl;            // 0 for lane >= cnt
            wls[h][64 + lane] = e1 * rl;
        }
        __syncthreads();

        #pragma unroll
        for (int u = 0; u < 8; ++u) {               // PV from registers
            float w = wls[g][wv + u * 4];
            union { uint2 u2; __half2 h[2]; } uv; uv.u2 = vv0[u];
            float2 f0 = __half22float2(uv.h[0]);
            float2 f1 = __half22float2(uv.h[1]);
            a0 = fmaf(w, f0.x, a0); a1 = fmaf(w, f0.y, a1);
            a2 = fmaf(w, f1.x, a2); a3 = fmaf(w, f1.y, a3);
        }
        if (two) {
            #pragma unroll
            for (int u = 0; u < 8; ++u) {
                float w = wls[g][wv + 32 + u * 4];
                union { uint2 u2; __half2 h[2]; } uv; uv.u2 = vv1[u];
                float2 f0 = __half22float2(uv.h[0]);
                float2 f1 = __half22float2(uv.h[1]);
                a0 = fmaf(w, f0.x, a0); a1 = fmaf(w, f0.y, a1);
                a2 = fmaf(w, f1.x, a2); a3 = fmaf(w, f1.y, a3);
            }
        }
    } else {
        // ======== SLOW PATH (cnt > 64): two gather rounds (R7 flow) ========
        for (int jb = wv; jb < cnt; jb += 32) {
            uint2 kv[8];
            #pragma unroll
            for (int u = 0; u < 8; ++u)
                kv[u] = ((const uint2*)(QKV + (size_t)nbrs[jb + u * 4] * NQKV + 256))[lane];
            #pragma unroll
            for (int u = 0; u < 8; ++u) {
                union { uint2 u2; f16x2 h[2]; } uk; uk.u2 = kv[u];
                float p = fdot2(q2a, uk.h[0], 0.f);
                p = fdot2(q2b, uk.h[1], p);
                #pragma unroll
                for (int off = 1; off < 16; off <<= 1) p += __shfl_xor(p, off);
                if (sub == 0) smat[g][jb + u * 4] = p;
            }
        }
        __syncthreads();
        {
            const int h = wv;
            float s0 = (lane < cnt)      ? smat[h][lane]      : -INFINITY;
            float s1 = (64 + lane < cnt) ? smat[h][64 + lane] : -INFINITY;
            float m = fmaxf(s0, s1);
            #pragma unroll
            for (int off = 32; off >= 1; off >>= 1) m = fmaxf(m, __shfl_xor(m, off));
            float e0 = expf(s0 - m);
            float e1 = expf(s1 - m);
            float l = e0 + e1;
            #pragma unroll
            for (int off = 32; off >= 1; off >>= 1) l += __shfl_xor(l, off);
            float rl = __frcp_rn(l);
            wls[h][lane]      = e0 * rl;
            wls[h][64 + lane] = e1 * rl;
            if (lane < SPAD - 128) wls[h][128 + lane] = 0.f;
        }
        __syncthreads();
        for (int jb = wv; jb < cnt; jb += 32) {
            uint2 vv[8]; float w[8];
            #pragma unroll
            for (int u = 0; u < 8; ++u) {
                w[u] = wls[g][jb + u * 4];
                vv[u] = ((const uint2*)(QKV + (size_t)nbrs[jb + u * 4] * NQKV + 512))[lane];
            }
            #pragma unroll
            for (int u = 0; u < 8; ++u) {
                union { uint2 u2; __half2 h[2]; } uv; uv.u2 = vv[u];
                float2 f0 = __half22float2(uv.h[0]);
                float2 f1 = __half22float2(uv.h[1]);
                a0 = fmaf(w[u], f0.x, a0); a1 = fmaf(w[u], f0.y, a1);
                a2 = fmaf(w[u], f1.x, a2); a3 = fmaf(w[u], f1.y, a3);
            }
        }
    }

    ((float4*)&ctxp[wv][0])[lane] = make_float4(a0, a1, a2, a3);
    __syncthreads();

    // ---- combine waves, split-bf16 write (weights pre-normalized) ----
    float out = ctxp[0][tid] + ctxp[1][tid] + ctxp[2][tid] + ctxp[3][tid];
    unsigned short hi = f2bf(out);
    Cm2[(size_t)row * 512 + tid]       = hi;
    Cm2[(size_t)row * 512 + 256 + tid] = f2bf(out - bf2f(hi));
}

// ---------------------------------------------------------------------------
extern "C" void kernel_launch(void* const* d_in, const int* in_sizes, int n_in,
                              void* d_out, int out_size, void* d_ws, size_t ws_size,
                              hipStream_t stream)
{
    const float* X  = (const float*)d_in[0];
    const float* Wq = (const float*)d_in[1];
    const float* bq = (const float*)d_in[2];
    const float* Wk = (const float*)d_in[3];
    const float* bk = (const float*)d_in[4];
    const float* Wv = (const float*)d_in[5];
    const float* bv = (const float*)d_in[6];
    const float* Wo = (const float*)d_in[7];
    const float* bo = (const float*)d_in[8];
    const int*   ei = (const int*)d_in[9];
    float* out = (float*)d_out;

    char* ws = (char*)d_ws;
    // lifetimes: bitmap (consumed by build_csr) aliases QKV (written later);
    //            A2 (consumed by QKV gemm) aliased by Cm2 (written by attn).
    __half*         QKV    = (__half*)ws;                         // 12.6 MB (region 25 MB)
    uint32_t*       bitmap = (uint32_t*)ws;                       // first 8 MB
    unsigned short* A2     = (unsigned short*)(ws + 25165824);    // 8 MB
    unsigned short* Cm2    = A2;
    unsigned short* W2Tq   = (unsigned short*)(ws + 33554432);    // 1179648 B
    unsigned short* W2To   = (unsigned short*)(ws + 34734080);    // 393216 B
    float*          biasq  = (float*)(ws + 35127296);             // 3072 B
    int*            nbrL   = (int*)(ws + 35130368);               // 4194304 B
    int*            cntL   = (int*)(ws + 39324672);               // 32768 B

    zero_kernel<<<2048, 256, 0, stream>>>((uint4*)bitmap);
    prep_kernel<<<12288, 256, 0, stream>>>(
        X, Wq, Wk, Wv, Wo, bq, bk, bv, ei, bitmap, A2, W2Tq, W2To, biasq);
    build_csr_kernel<<<NN / 4, 256, 0, stream>>>(bitmap, nbrL, cntL);

    mfma_gemm_kernel<128, true><<<384, 256, 0, stream>>>(
        A2, W2Tq, biasq, QKV, NQKV);

    attn_kernel<<<NN, 256, 0, stream>>>(QKV, nbrL, cntL, Cm2);

    mfma_gemm_kernel<64, false><<<256, 256, 0, stream>>>(
        Cm2, W2To, bo, out, HID);
}

// Round 9
// 79.423 us; speedup vs baseline: 1.4009x; 1.4009x over previous
//
#include <hip/hip_runtime.h>
#include <hip/hip_fp16.h>
#include <stdint.h>

#define NN 8192          // nodes
#define HID 256          // hidden
#define NH 4             // heads
#define HD 64            // head dim
#define NE 262144        // edges
#define WPR (NN / 32)    // bitmap words per row = 256
#define CAP 128          // max neighbors per row (Binomial(262k,1/8192): max ~57)
#define NQKV 768         // fused QKV output width

typedef __attribute__((ext_vector_type(8))) short s16x8;      // 8 halves (4 VGPRs)
typedef __attribute__((ext_vector_type(4))) float f32x4;      // MFMA C/D frag
typedef _Float16 f16x2 __attribute__((ext_vector_type(2)));   // v_dot2 operand

__device__ __forceinline__ float fdot2(f16x2 a, f16x2 b, float c) {
#if __has_builtin(__builtin_amdgcn_fdot2)
    return __builtin_amdgcn_fdot2(a, b, c, false);
#else
    return c + (float)a.x * (float)b.x + (float)a.y * (float)b.y;
#endif
}

__device__ __forceinline__ void gload_lds16(const unsigned short* g, unsigned short* l) {
    __builtin_amdgcn_global_load_lds(
        (const __attribute__((address_space(1))) unsigned int*)g,
        (__attribute__((address_space(3))) unsigned int*)l, 16, 0, 0);
}

// ---------------------------------------------------------------------------
// Zero the bitmap: 2048 blocks x 256 thr x 16B = 8 MB
// ---------------------------------------------------------------------------
__global__ __launch_bounds__(256) void zero_kernel(uint4* __restrict__ p)
{
    p[blockIdx.x * 256 + threadIdx.x] = make_uint4(0, 0, 0, 0);
}

// ---------------------------------------------------------------------------
// Fused prep: [0,1024) edge scatter | [1024,3072) X->fp16 (4/thr)
//             [3072,4096) W^T->fp16 + qkv bias
// ---------------------------------------------------------------------------
__global__ __launch_bounds__(256) void prep_kernel(
    const float* __restrict__ X,
    const float* __restrict__ Wq, const float* __restrict__ Wk,
    const float* __restrict__ Wv, const float* __restrict__ Wo,
    const float* __restrict__ bq, const float* __restrict__ bk,
    const float* __restrict__ bv, const int* __restrict__ ei,
    uint32_t* __restrict__ bitmap, unsigned short* __restrict__ Xh,
    unsigned short* __restrict__ W2Tq, unsigned short* __restrict__ W2To,
    float* __restrict__ biasq)
{
    const int b = blockIdx.x, tid = threadIdx.x;
    if (b < 1024) {                                   // ---- edge scatter ----
        int e = b * 256 + tid;
        int r = ei[e];
        int c = ei[NE + e];
        atomicOr(&bitmap[(size_t)r * WPR + (c >> 5)], 1u << (c & 31));
    } else if (b < 3072) {                            // ---- X -> fp16 ----
        int i4 = ((b - 1024) * 256 + tid) * 4;        // covers NN*HID exactly
        float4 x = *(const float4*)(X + i4);
        __half2 h0 = __floats2half2_rn(x.x, x.y);
        __half2 h1 = __floats2half2_rn(x.z, x.w);
        uint2 w;
        w.x = *(unsigned*)&h0;
        w.y = *(unsigned*)&h1;
        *(uint2*)(Xh + i4) = w;
    } else {                                          // ---- W^T -> fp16 ----
        int lin = (b - 3072) * 256 + tid;             // 262144 = 1024*256
        int n = lin >> 8, k = lin & 255;
        const float* W; int ns; unsigned short* dst;
        if (n < NQKV) {
            W  = (n < 256) ? Wq : (n < 512) ? Wk : Wv;
            ns = n & 255;
            dst = W2Tq + (size_t)n * HID + k;
            if (k == 0) {
                const float* bsrc = (n < 256) ? bq : (n < 512) ? bk : bv;
                biasq[n] = bsrc[ns];
            }
        } else {
            W = Wo; ns = n - NQKV;
            dst = W2To + (size_t)ns * HID + k;
        }
        __half h = __float2half(W[(size_t)k * HID + ns]);
        *dst = *(unsigned short*)&h;
    }
}

// ---------------------------------------------------------------------------
// fp16 MFMA GEMM: C[8192][N] = A[8192][256] * B^T[N][256] + bias (fp32 acc)
// BM=128; BN template (128 QKV / 64 out-proj). 4 waves 2x2; 16x16x32 f16.
// 1D grid + bijective XCD swizzle (nwg % 8 == 0).
// ---------------------------------------------------------------------------
template<int BN, bool HALF_OUT>
__global__ __launch_bounds__(256) void mfma_gemm_kernel(
    const unsigned short* __restrict__ A, const unsigned short* __restrict__ BT,
    const float* __restrict__ bias, void* __restrict__ Cv, int N)
{
    constexpr int NFR = BN / 32;                    // N-frags per wave
    __shared__ __align__(16) unsigned short Alds[128 * 32];
    __shared__ __align__(16) unsigned short Blds[BN * 32];

    const int tid  = threadIdx.x;
    const int lane = tid & 63, wave = tid >> 6;
    const int wm = wave >> 1, wn = wave & 1;

    const int nwg = gridDim.x;
    const int orig = blockIdx.x;
    const int q8 = nwg >> 3;
    const int id = (orig & 7) * q8 + (orig >> 3);   // XCD-contiguous chunks
    const int m0 = (id & 63) * 128;                 // 64 M-tiles (8192/128)
    const int n0 = (id >> 6) * BN;

    const int r0 = tid >> 2, cc0 = tid & 3;
    const int r1 = (tid + 256) >> 2, cc1 = (tid + 256) & 3;

    f32x4 acc[4][NFR];
    #pragma unroll
    for (int i = 0; i < 4; ++i)
        #pragma unroll
        for (int j = 0; j < NFR; ++j)
            acc[i][j] = (f32x4){0.f, 0.f, 0.f, 0.f};

    for (int step = 0; step < 8; ++step) {
        const int kk = step * 32;
        __syncthreads();
        gload_lds16(A + (size_t)(m0 + r0) * HID + kk + cc0 * 8, &Alds[tid * 8]);
        gload_lds16(A + (size_t)(m0 + r1) * HID + kk + cc1 * 8, &Alds[(tid + 256) * 8]);
        gload_lds16(BT + (size_t)(n0 + r0) * HID + kk + cc0 * 8, &Blds[tid * 8]);
        if constexpr (BN == 128)
            gload_lds16(BT + (size_t)(n0 + r1) * HID + kk + cc1 * 8, &Blds[(tid + 256) * 8]);
        __syncthreads();

        s16x8 af[4], bfr[NFR];
        #pragma unroll
        for (int i = 0; i < 4; ++i)
            af[i] = *(const s16x8*)&Alds[(wm * 64 + i * 16 + (lane & 15)) * 32 + (lane >> 4) * 8];
        #pragma unroll
        for (int j = 0; j < NFR; ++j)
            bfr[j] = *(const s16x8*)&Blds[(wn * (BN / 2) + j * 16 + (lane & 15)) * 32 + (lane >> 4) * 8];
        #pragma unroll
        for (int i = 0; i < 4; ++i)
            #pragma unroll
            for (int j = 0; j < NFR; ++j)
                acc[i][j] = __builtin_amdgcn_mfma_f32_16x16x32_f16(af[i], bfr[j], acc[i][j], 0, 0, 0);
    }

    // epilogue: C/D layout col=lane&15, row=(lane>>4)*4+reg
    #pragma unroll
    for (int i = 0; i < 4; ++i) {
        #pragma unroll
        for (int j = 0; j < NFR; ++j) {
            int gcol = n0 + wn * (BN / 2) + j * 16 + (lane & 15);
            float bb = bias[gcol];
            #pragma unroll
            for (int r = 0; r < 4; ++r) {
                int grow = m0 + wm * 64 + i * 16 + (lane >> 4) * 4 + r;
                float v = acc[i][j][r] + bb;
                if constexpr (HALF_OUT)
                    ((__half*)Cv)[(size_t)grow * N + gcol] = __float2half(v);
                else
                    ((float*)Cv)[(size_t)grow * N + gcol] = v;
            }
        }
    }
}

// ---------------------------------------------------------------------------
// Compact bitmap rows into capped neighbor lists. One wave per row.
// ---------------------------------------------------------------------------
__global__ __launch_bounds__(256) void build_csr_kernel(
    const uint32_t* __restrict__ bitmap, int* __restrict__ nbr, int* __restrict__ cnt)
{
    const int row = blockIdx.x * 4 + (threadIdx.x >> 6);
    const int lane = threadIdx.x & 63;
    const uint32_t* rp = bitmap + (size_t)row * WPR + lane * 4;
    uint32_t w0 = rp[0], w1 = rp[1], w2 = rp[2], w3 = rp[3];
    int pc = __popc(w0) + __popc(w1) + __popc(w2) + __popc(w3);
    int scan = pc;
    #pragma unroll
    for (int off = 1; off < 64; off <<= 1) {
        int t = __shfl_up(scan, off);
        if (lane >= off) scan += t;
    }
    int idx = scan - pc;
    int* dst = nbr + (size_t)row * CAP;
    const int base = lane * 128;
    uint32_t ws4[4] = {w0, w1, w2, w3};
    #pragma unroll
    for (int i = 0; i < 4; ++i) {
        uint32_t w = ws4[i];
        int cb = base + i * 32;
        while (w) {
            int b = __ffs(w) - 1;
            if (idx < CAP) dst[idx] = cb + b;
            ++idx;
            w &= w - 1;
        }
    }
    if (lane == 63) cnt[row] = min(scan, CAP);
}

// ---------------------------------------------------------------------------
// Sparse attention, WAVE-PER-ROW, zero LDS, zero barriers.
// Lane l owns cols 4l..4l+3 (head g=l>>4). Per batch of 8 neighbors:
// 16 coalesced 512B row loads in flight; scores via 16-lane shfl reduce
// (score lands in ALL lanes of the head group); online softmax + PV in
// registers. Block = 4 independent waves = 4 rows.
// ---------------------------------------------------------------------------
__global__ __launch_bounds__(256) void attn_kernel(
    const __half* __restrict__ QKV, const int* __restrict__ nbr,
    const int* __restrict__ cntg, __half* __restrict__ ctx)
{
    const int row  = blockIdx.x * 4 + (threadIdx.x >> 6);
    const int lane = threadIdx.x & 63;
    const int cnt  = cntg[row];

    // Q slice: halves 4l..4l+3 (head g slice)
    uint2 qraw = ((const uint2*)(QKV + (size_t)row * NQKV))[lane];
    union { uint2 u2; f16x2 h[2]; } uq; uq.u2 = qraw;
    const f16x2 q2a = uq.h[0], q2b = uq.h[1];

    float m = -INFINITY, l = 0.f;
    float a0 = 0.f, a1 = 0.f, a2 = 0.f, a3 = 0.f;

    for (int j0 = 0; j0 < cnt; j0 += 64) {
        int mynb = (j0 + lane < cnt) ? nbr[(size_t)row * CAP + j0 + lane] : 0;
        const int nb = min(64, cnt - j0);
        for (int b = 0; b < nb; b += 8) {
            int idx[8];
            #pragma unroll
            for (int u = 0; u < 8; ++u) idx[u] = __shfl(mynb, b + u);
            uint2 kv[8], vv[8];
            #pragma unroll
            for (int u = 0; u < 8; ++u) {          // 16 loads in flight
                const __half* base = QKV + (size_t)idx[u] * NQKV;
                kv[u] = ((const uint2*)(base + 256))[lane];
                vv[u] = ((const uint2*)(base + 512))[lane];
            }
            float s[8];
            #pragma unroll
            for (int u = 0; u < 8; ++u) {
                union { uint2 u2; f16x2 h[2]; } uk; uk.u2 = kv[u];
                float p = fdot2(q2a, uk.h[0], 0.f);
                p = fdot2(q2b, uk.h[1], p);
                #pragma unroll
                for (int off = 1; off < 16; off <<= 1) p += __shfl_xor(p, off);
                s[u] = (b + u < nb) ? p * 0.125f : -INFINITY;
            }
            float bm = s[0];
            #pragma unroll
            for (int u = 1; u < 8; ++u) bm = fmaxf(bm, s[u]);
            float mn = fmaxf(m, bm);               // finite (>=1 valid score)
            float sc = expf(m - mn);               // first batch: exp(-inf)=0
            a0 *= sc; a1 *= sc; a2 *= sc; a3 *= sc; l *= sc;
            #pragma unroll
            for (int u = 0; u < 8; ++u) {
                float w = expf(s[u] - mn);         // masked: exp(-inf)=0
                l += w;
                union { uint2 u2; __half2 h[2]; } uv; uv.u2 = vv[u];
                float2 f0 = __half22float2(uv.h[0]);
                float2 f1 = __half22float2(uv.h[1]);
                a0 = fmaf(w, f0.x, a0); a1 = fmaf(w, f0.y, a1);
                a2 = fmaf(w, f1.x, a2); a3 = fmaf(w, f1.y, a3);
            }
            m = mn;
        }
    }

    uint2 outw = make_uint2(0u, 0u);               // cnt==0 -> zeros
    if (cnt > 0) {
        float rl = 1.f / l;
        __half2 o0 = __floats2half2_rn(a0 * rl, a1 * rl);
        __half2 o1 = __floats2half2_rn(a2 * rl, a3 * rl);
        outw.x = *(unsigned*)&o0;
        outw.y = *(unsigned*)&o1;
    }
    ((uint2*)(ctx + (size_t)row * HID))[lane] = outw;
}

// ---------------------------------------------------------------------------
extern "C" void kernel_launch(void* const* d_in, const int* in_sizes, int n_in,
                              void* d_out, int out_size, void* d_ws, size_t ws_size,
                              hipStream_t stream)
{
    const float* X  = (const float*)d_in[0];
    const float* Wq = (const float*)d_in[1];
    const float* bq = (const float*)d_in[2];
    const float* Wk = (const float*)d_in[3];
    const float* bk = (const float*)d_in[4];
    const float* Wv = (const float*)d_in[5];
    const float* bv = (const float*)d_in[6];
    const float* Wo = (const float*)d_in[7];
    const float* bo = (const float*)d_in[8];
    const int*   ei = (const int*)d_in[9];
    float* out = (float*)d_out;

    char* ws = (char*)d_ws;
    // lifetimes: bitmap (consumed by build_csr) aliases QKV (written by gemm1);
    //            Xh (consumed by gemm1) aliased by ctx (written by attn).
    __half*         QKV    = (__half*)ws;                         // 12,582,912 B
    uint32_t*       bitmap = (uint32_t*)ws;                       // first 8 MB
    unsigned short* Xh     = (unsigned short*)(ws + 16777216);    // 4 MB
    __half*         ctx    = (__half*)Xh;                         // alias
    unsigned short* W2Tq   = (unsigned short*)(ws + 20971520);    // 393,216 B
    unsigned short* W2To   = (unsigned short*)(ws + 21364736);    // 131,072 B
    float*          biasq  = (float*)(ws + 21495808);             // 3,072 B
    int*            nbrL   = (int*)(ws + 21498880);               // 4 MB
    int*            cntL   = (int*)(ws + 25693184);               // 32,768 B

    zero_kernel<<<2048, 256, 0, stream>>>((uint4*)bitmap);
    prep_kernel<<<4096, 256, 0, stream>>>(
        X, Wq, Wk, Wv, Wo, bq, bk, bv, ei, bitmap, Xh, W2Tq, W2To, biasq);
    build_csr_kernel<<<NN / 4, 256, 0, stream>>>(bitmap, nbrL, cntL);

    mfma_gemm_kernel<128, true><<<384, 256, 0, stream>>>(
        Xh, W2Tq, biasq, QKV, NQKV);

    attn_kernel<<<NN / 4, 256, 0, stream>>>(QKV, nbrL, cntL, ctx);

    mfma_gemm_kernel<64, false><<<256, 256, 0, stream>>>(
        (const unsigned short*)ctx, W2To, bo, out, HID);
}